// Round 9
// baseline (203.110 us; speedup 1.0000x reference)
//
#include <hip/hip_runtime.h>
#include <stdint.h>

// QuantizedConv2d int8 implicit GEMM via MFMA i32_16x16x64_i8.
// N=32, C_in=128, H=W=56, C_out=256, 3x3, pad 1, stride 1.
// Output int8 values stored as int32 (harness reads integer outputs as np.int32).
//
// R19: ratio-4. R13-R18 all landed at qconv ~49 us ~= pipe SUM; the common
// factor was the ratio-2 iter body (2 ds_read + 4 MFMA): each wave supplies
// only 4 MFMAs per ~50-cy issue window vs 82 cy of matrix-pipe demand ->
// per-wave supply was the limiter at every occupancy tried. Also, R14/R15's
// spill was self-inflicted: "+v" asm pins forced the B panel into the arch-
// VGPR half of the unified file; unpinned accumulators go to AGPRs (m97).
// Changes:
//  - Wave = 7 mt x 4 ct (112 M x 64 co); block = 4 waves = 112 M x 256 co.
//    896 one-shot blocks = 32 n x 28 slabs. Iter body = 2 ds_read + 8 MFMA
//    (~163 cy matrix work per a-pair: one wave nearly fills its SIMD's
//    matrix pipe; LDS reads/CU halve to ~8.8 us, well under MFMA 15 us).
//  - acc = 28 v4i, NO pins anywhere -> allocator free to use AGPRs.
//  - B streamed JIT 1 tap ahead (8 v4i in flight, laundered base pointer
//    only); A-prefetch depth-1 (8 MFMAs cover the ~120-cy LDS latency).
//  - Same 32-KB A slab + single __syncthreads + direct stores + XCD swizzle.

#define NB 32
#define CI 128
#define HH 56
#define WW 56
#define CO 256
#define SPA (HH * WW)              // 3136 = 28 slabs x 112 (2 image rows each)
#define HP 58
#define WP 64
#define XP2_BYTES (NB * HP * WP * CI)      // 15204352
#define BP_BYTES (9 * 2 * 4 * CO * 16)     // 294912
#define ABUF (4 * 8192)                    // 4 padded rows = 32 KB

typedef int v4i __attribute__((ext_vector_type(4)));

// ---- prep (unchanged from R10) ----
// [0,1792): pack one (n,h) row -> padded NHWC int8, pad byte = zp, XOR-swizzled
// [1792,1856): border h-rows = zp
// [1856,2112): weight pack + BG[co] = bias - zp*S9
__global__ __launch_bounds__(256) void prep_kernel(
    const int* __restrict__ x, const int* __restrict__ wgt,
    const int* __restrict__ bias, const int* __restrict__ zpi,
    int8_t* __restrict__ xp2, int8_t* __restrict__ bp, int* __restrict__ BG)
{
    __shared__ int sm[1824];
    const int tid = threadIdx.x, bid = blockIdx.x;
    const int zp = *zpi;
    const int zp4 = (zp & 255) * 0x01010101;

    if (bid < HH * NB) {
        const int n = bid / HH, h = bid % HH;
        #pragma unroll
        for (int it = 0; it < 7; ++it) {
            int j = tid + it * 256;                 // 1792 = 128 ci x 14 w4
            int ci = j / 14, w4 = j - ci * 14;
            const v4i v = *(const v4i*)(x + ((n * CI + ci) * HH + h) * WW + w4 * 4);
            sm[w4 * 130 + ci] = (v.x & 255) | ((v.y & 255) << 8) |
                                ((v.z & 255) << 16) | (v.w << 24);
        }
        __syncthreads();
        int* od = (int*)xp2 + (n * HP + h + 1) * (WP * CI / 4);  // 2048 dwords
        #pragma unroll
        for (int it = 0; it < 8; ++it) {
            int j = tid + it * 256;                 // j = widx*32 + ci4
            int widx = j >> 5, ci4 = j & 31;
            int val = zp4;                          // pad value = zp
            if (widx >= 1 && widx <= WW) {
                int w = widx - 1;
                int base = (w >> 2) * 130 + ci4 * 4;
                int sh = (w & 3) * 8;
                val = ((sm[base] >> sh) & 0xff) | (((sm[base+1] >> sh) & 0xff) << 8) |
                      (((sm[base+2] >> sh) & 0xff) << 16) | ((sm[base+3] >> sh) << 24);
            }
            od[j ^ ((widx & 7) << 2)] = val;        // XOR-swizzle 16-B units
        }
    } else if (bid < HH * NB + 2 * NB) {
        const int z = bid - HH * NB;
        const int n = z >> 1, hidx = (z & 1) ? (HP - 1) : 0;
        int* od = (int*)xp2 + (n * HP + hidx) * (WP * CI / 4);
        #pragma unroll
        for (int it = 0; it < 8; ++it) od[tid + it * 256] = zp4;  // zp border rows
    } else {
        const int co = bid - (HH * NB + 2 * NB);
        for (int j = tid; j < 1152; j += 256) sm[j] = wgt[co * 1152 + j];  // [ci][9]
        __syncthreads();
        for (int j = tid; j < 288; j += 256) {      // 9t x 2c64 x 4q x 4j4
            int j4 = j & 3, q = (j >> 2) & 3, c64 = (j >> 4) & 1, t = j >> 5;
            int ci = c64 * 64 + q * 16 + j4 * 4;
            int b0 = sm[(ci + 0) * 9 + t] & 255, b1 = sm[(ci + 1) * 9 + t] & 255;
            int b2 = sm[(ci + 2) * 9 + t] & 255, b3 = sm[(ci + 3) * 9 + t];
            ((int*)bp)[((t * 2 + c64) * 4 + q) * 1024 + co * 4 + j4] =
                b0 | (b1 << 8) | (b2 << 16) | (b3 << 24);
        }
        if (tid < 9) {
            int s = 0;
            for (int ci = 0; ci < CI; ++ci) s += sm[ci * 9 + tid];
            sm[1152 + tid] = s;
        }
        __syncthreads();
        if (tid == 0) {
            int s9 = 0;
            for (int t = 0; t < 9; ++t) s9 += sm[1152 + t];
            BG[co] = bias[co] - zp * s9;            // cls-independent correction
        }
    }
}

// ---- main: 896 one-shot blocks x 256 thr; block = 112M x 256co ----
// wave = 112M x 64co (7 mt x 4 ct): 8 MFMA per a0/a1 LDS pair.
__global__ __launch_bounds__(256) void qconv_mfma(
    const int8_t* __restrict__ xp2, const int8_t* __restrict__ bp,
    const int* __restrict__ BG,
    const float* __restrict__ si, const float* __restrict__ sw,
    const float* __restrict__ so, const int* __restrict__ zpo,
    int* __restrict__ out)
{
    const int tid  = threadIdx.x, lane = tid & 63, wid = tid >> 6;
    const int quad = lane >> 4, lo16 = lane & 15;
    const int bid  = blockIdx.x;                    // 896 blocks
    const int xcd  = bid & 7, idx = bid >> 3;       // idx 0..111 per XCD
    const int n    = xcd * 4 + (idx & 3);           // 4 n-images per XCD (L2)
    const int s2   = idx >> 2;                      // slab 0..27
    const int cw   = wid * 64;                      // wave co base (64 co)

    __shared__ __attribute__((aligned(16))) int8_t Asm[ABUF];  // 32 KB

    // ---- stage this tile's A slab (4 padded rows, 32 KB) ----
    const int8_t* src0 = xp2 + (((size_t)n * HP + 2 * s2) << 13);
    #pragma unroll
    for (int k = 0; k < 8; ++k) {
        const int u = wid + 4 * k;                  // 32 x 1-KB units
        __builtin_amdgcn_global_load_lds(
            (const __attribute__((address_space(1))) void*)(src0 + (u << 10) + lane * 16),
            (__attribute__((address_space(3))) void*)(&Asm[u << 10]), 16, 0, 0);
    }

    int bgv[4];
    #pragma unroll
    for (int ct = 0; ct < 4; ++ct) bgv[ct] = BG[cw + ct * 16 + lo16];
    const float rs = (*si) * (*sw) / (*so);
    const float zo = (float)(*zpo);

    // per-mt geometry (slab-local): base offset + packed swizzle per tap-col
    int boff[7], sw3[7];
    #pragma unroll
    for (int mt = 0; mt < 7; ++mt) {
        const int ml = mt * 16 + lo16;              // 0..111 within slab
        const int srow = ml / 56, scol = ml - srow * 56;
        boff[mt] = srow * 8192 + scol * 128 + quad * 16;
        int t0 = ((scol + 0) & 7) << 4, t1 = ((scol + 1) & 7) << 4,
            t2 = ((scol + 2) & 7) << 4;
        sw3[mt] = t0 | (t1 << 8) | (t2 << 16);      // swizzle per dc, packed
    }

    // B stream base for this wave: page (t*8 + c64*4 + quad), entry co*16
    const int8_t* bwav = bp + ((size_t)quad << 12) + ((cw + lo16) << 4);

    int* optr = out + ((size_t)n * CO + cw + lo16) * SPA + quad * 4;

    // issue the 8 B fragments for tap tp (laundered base: stops LICM/clustering)
    #define BLOAD(tp) {                                                        \
        const int8_t* bb = bwav + ((tp) * 8 << 12);                            \
        asm volatile("" : "+v"(bb));                                           \
        bt[tp][0] = *(const v4i*)(bb);                                         \
        bt[tp][1] = *(const v4i*)(bb + 256);                                   \
        bt[tp][2] = *(const v4i*)(bb + 512);                                   \
        bt[tp][3] = *(const v4i*)(bb + 768);                                   \
        bt[tp][4] = *(const v4i*)(bb + 16384);                                 \
        bt[tp][5] = *(const v4i*)(bb + 16384 + 256);                           \
        bt[tp][6] = *(const v4i*)(bb + 16384 + 512);                           \
        bt[tp][7] = *(const v4i*)(bb + 16384 + 768);                           \
    }

    // swizzled LDS address for (tp, mt)
    #define AADDR(tp, mt) \
        ((boff[mt] + ((tp) / 3) * 8192 + ((tp) % 3) * 128) ^ \
         ((sw3[mt] >> (8 * ((tp) % 3))) & 0x70))

    v4i bt[9][8];                                   // streamed B (2 taps live)
    BLOAD(0);

    v4i acc[7][4];
    #pragma unroll
    for (int mt = 0; mt < 7; ++mt)
        #pragma unroll
        for (int ct = 0; ct < 4; ++ct) acc[mt][ct] = (v4i){0, 0, 0, 0};

    __syncthreads();                                // A slab staged

    // ---- K-loop: flat 63 iters (tp = it/7, mt = it%7), depth-1 A pipeline.
    //      (it+1)'s 2 ds_reads issue under it's 8 MFMAs (~163 cy cover). ----
    v4i a0p[2], a1p[2];
    { const int p = AADDR(0, 0);
      a0p[0] = *(const v4i*)(Asm + p); a1p[0] = *(const v4i*)(Asm + (p ^ 64)); }

    #pragma unroll
    for (int it = 0; it < 63; ++it) {
        const int tp = it / 7, mt = it % 7;
        if (mt == 0 && tp + 1 <= 8) BLOAD(tp + 1);  // B one tap ahead
        if (it + 1 < 63) {                          // A one iter ahead
            const int tp1 = (it + 1) / 7, mt1 = (it + 1) % 7;
            const int p = AADDR(tp1, mt1);
            a0p[(it + 1) & 1] = *(const v4i*)(Asm + p);
            a1p[(it + 1) & 1] = *(const v4i*)(Asm + (p ^ 64));
        }
        const v4i a0 = a0p[it & 1], a1 = a1p[it & 1];
        #pragma unroll
        for (int ct = 0; ct < 4; ++ct)
            acc[mt][ct] = __builtin_amdgcn_mfma_i32_16x16x64_i8(a0, bt[tp][ct], acc[mt][ct], 0, 0, 0);
        #pragma unroll
        for (int ct = 0; ct < 4; ++ct)
            acc[mt][ct] = __builtin_amdgcn_mfma_i32_16x16x64_i8(a1, bt[tp][4 + ct], acc[mt][ct], 0, 0, 0);
    }
    #undef BLOAD
    #undef AADDR

    // ---- epilogue: requant + 28 direct v4i stores; kernel ends ----
    const int m0 = s2 * 112;
    #pragma unroll
    for (int mt = 0; mt < 7; ++mt) {
        #pragma unroll
        for (int ct = 0; ct < 4; ++ct) {
            v4i vv;
            #pragma unroll
            for (int i4 = 0; i4 < 4; ++i4) {        // C/D row = quad*4+i4
                float yv = rintf((float)(acc[mt][ct][i4] + bgv[ct]) * rs + zo);
                yv = fminf(fmaxf(yv, -128.f), 127.f);
                vv[i4] = (int)yv;
            }
            *(v4i*)(optr + ct * 16 * SPA + m0 + mt * 16) = vv;
        }
    }
}

extern "C" void kernel_launch(void* const* d_in, const int* in_sizes, int n_in,
                              void* d_out, int out_size, void* d_ws, size_t ws_size,
                              hipStream_t stream) {
    const int*   x    = (const int*)d_in[0];
    const int*   wgt  = (const int*)d_in[1];
    const int*   bias = (const int*)d_in[2];
    const float* si   = (const float*)d_in[3];
    const float* sw   = (const float*)d_in[4];
    const float* so   = (const float*)d_in[5];
    const int*   zpi  = (const int*)d_in[6];
    const int*   zpo  = (const int*)d_in[7];
    int* out = (int*)d_out;

    int8_t* xp2 = (int8_t*)d_ws;
    int8_t* bp  = xp2 + XP2_BYTES;
    int*    bg  = (int*)(bp + BP_BYTES);

    prep_kernel<<<HH * NB + 2 * NB + CO, 256, 0, stream>>>(x, wgt, bias, zpi, xp2, bp, bg);
    qconv_mfma<<<896, 256, 0, stream>>>(xp2, bp, bg, si, sw, so, zpo, out);
}

// Round 10
// 191.283 us; speedup vs baseline: 1.0618x; 1.0618x over previous
//
#include <hip/hip_runtime.h>
#include <stdint.h>

// QuantizedConv2d int8 implicit GEMM via MFMA i32_16x16x64_i8.
// N=32, C_in=128, H=W=56, C_out=256, 3x3, pad 1, stride 1.
// Output int8 values stored as int32 (harness reads integer outputs as np.int32).
//
// R20: ratio-4 with a <=256-total register footprint. R19's failure mode:
// acc went to AGPRs (VGPR_Count 136 hid them) and 136 VGPR + 128 AGPR = 264
// > 256 in gfx950's UNIFIED file -> 1 wave/SIMD -> serial phases, 66 us.
// (Same trap as R10: 132+112.) Changes:
//  - sw3[] deleted: swizzle derived from the offset itself,
//    phys = off ^ (((off>>7)&7)<<4)  (bits 7..9 of off == padded col mod 8
//    because the row stride 8192 == 0 mod 1024). -7 VGPR.
//  - bt[2][8] explicit tap double-buffer (compile-time tp&1): B-live = 64.
//  - arch ~115 VGPR + 112 AGPR (acc, unpinned) ~= 227 <= 256 -> 2 waves/SIMD;
//    amdgpu_waves_per_eu(2) declares the cap (feasible now, unlike R15).
//  - 1792 one-shot blocks x 128 thr (block = n, co128, slab; wave = 7mt x 4ct,
//    8 MFMA per a0/a1 LDS pair): 4 resident blocks/CU (4 x 32 KB LDS, 8
//    waves), 7 blocks/CU total -> fine-grained backfill + phase diversity.
// Per-CU work: MFMA 15 us, LDS-read 8.8 us, VALU ~6 us -> floor ~15-20 us.

#define NB 32
#define CI 128
#define HH 56
#define WW 56
#define CO 256
#define SPA (HH * WW)              // 3136 = 28 slabs x 112 (2 image rows each)
#define HP 58
#define WP 64
#define XP2_BYTES (NB * HP * WP * CI)      // 15204352
#define BP_BYTES (9 * 2 * 4 * CO * 16)     // 294912
#define ABUF (4 * 8192)                    // 4 padded rows = 32 KB

typedef int v4i __attribute__((ext_vector_type(4)));

// ---- prep (unchanged from R10) ----
// [0,1792): pack one (n,h) row -> padded NHWC int8, pad byte = zp, XOR-swizzled
// [1792,1856): border h-rows = zp
// [1856,2112): weight pack + BG[co] = bias - zp*S9
__global__ __launch_bounds__(256) void prep_kernel(
    const int* __restrict__ x, const int* __restrict__ wgt,
    const int* __restrict__ bias, const int* __restrict__ zpi,
    int8_t* __restrict__ xp2, int8_t* __restrict__ bp, int* __restrict__ BG)
{
    __shared__ int sm[1824];
    const int tid = threadIdx.x, bid = blockIdx.x;
    const int zp = *zpi;
    const int zp4 = (zp & 255) * 0x01010101;

    if (bid < HH * NB) {
        const int n = bid / HH, h = bid % HH;
        #pragma unroll
        for (int it = 0; it < 7; ++it) {
            int j = tid + it * 256;                 // 1792 = 128 ci x 14 w4
            int ci = j / 14, w4 = j - ci * 14;
            const v4i v = *(const v4i*)(x + ((n * CI + ci) * HH + h) * WW + w4 * 4);
            sm[w4 * 130 + ci] = (v.x & 255) | ((v.y & 255) << 8) |
                                ((v.z & 255) << 16) | (v.w << 24);
        }
        __syncthreads();
        int* od = (int*)xp2 + (n * HP + h + 1) * (WP * CI / 4);  // 2048 dwords
        #pragma unroll
        for (int it = 0; it < 8; ++it) {
            int j = tid + it * 256;                 // j = widx*32 + ci4
            int widx = j >> 5, ci4 = j & 31;
            int val = zp4;                          // pad value = zp
            if (widx >= 1 && widx <= WW) {
                int w = widx - 1;
                int base = (w >> 2) * 130 + ci4 * 4;
                int sh = (w & 3) * 8;
                val = ((sm[base] >> sh) & 0xff) | (((sm[base+1] >> sh) & 0xff) << 8) |
                      (((sm[base+2] >> sh) & 0xff) << 16) | ((sm[base+3] >> sh) << 24);
            }
            od[j ^ ((widx & 7) << 2)] = val;        // XOR-swizzle 16-B units
        }
    } else if (bid < HH * NB + 2 * NB) {
        const int z = bid - HH * NB;
        const int n = z >> 1, hidx = (z & 1) ? (HP - 1) : 0;
        int* od = (int*)xp2 + (n * HP + hidx) * (WP * CI / 4);
        #pragma unroll
        for (int it = 0; it < 8; ++it) od[tid + it * 256] = zp4;  // zp border rows
    } else {
        const int co = bid - (HH * NB + 2 * NB);
        for (int j = tid; j < 1152; j += 256) sm[j] = wgt[co * 1152 + j];  // [ci][9]
        __syncthreads();
        for (int j = tid; j < 288; j += 256) {      // 9t x 2c64 x 4q x 4j4
            int j4 = j & 3, q = (j >> 2) & 3, c64 = (j >> 4) & 1, t = j >> 5;
            int ci = c64 * 64 + q * 16 + j4 * 4;
            int b0 = sm[(ci + 0) * 9 + t] & 255, b1 = sm[(ci + 1) * 9 + t] & 255;
            int b2 = sm[(ci + 2) * 9 + t] & 255, b3 = sm[(ci + 3) * 9 + t];
            ((int*)bp)[((t * 2 + c64) * 4 + q) * 1024 + co * 4 + j4] =
                b0 | (b1 << 8) | (b2 << 16) | (b3 << 24);
        }
        if (tid < 9) {
            int s = 0;
            for (int ci = 0; ci < CI; ++ci) s += sm[ci * 9 + tid];
            sm[1152 + tid] = s;
        }
        __syncthreads();
        if (tid == 0) {
            int s9 = 0;
            for (int t = 0; t < 9; ++t) s9 += sm[1152 + t];
            BG[co] = bias[co] - zp * s9;            // cls-independent correction
        }
    }
}

// ---- main: 1792 one-shot blocks x 128 thr; block = 112M x 128co ----
// wave = 112M x 64co (7 mt x 4 ct): 8 MFMA per a0/a1 LDS pair.
__global__ __launch_bounds__(128)
__attribute__((amdgpu_waves_per_eu(2)))             // cap: <=256 unified regs/wave
void qconv_mfma(
    const int8_t* __restrict__ xp2, const int8_t* __restrict__ bp,
    const int* __restrict__ BG,
    const float* __restrict__ si, const float* __restrict__ sw,
    const float* __restrict__ so, const int* __restrict__ zpo,
    int* __restrict__ out)
{
    const int tid  = threadIdx.x, lane = tid & 63, wid = tid >> 6;
    const int quad = lane >> 4, lo16 = lane & 15;
    const int bid  = blockIdx.x;                    // 1792 blocks
    const int xcd  = bid & 7, idx = bid >> 3;       // idx 0..223 per XCD
    const int n    = xcd * 4 + (idx & 3);           // 4 n-images per XCD (L2)
    const int cb   = (idx >> 2) & 1;
    const int s2   = idx >> 3;                      // slab 0..27
    const int cw   = cb * 128 + wid * 64;           // wave co base (64 co)

    __shared__ __attribute__((aligned(16))) int8_t Asm[ABUF];  // 32 KB

    // ---- stage this tile's A slab (4 padded rows, 32 KB), 2 waves ----
    const int8_t* src0 = xp2 + (((size_t)n * HP + 2 * s2) << 13);
    #pragma unroll
    for (int k = 0; k < 16; ++k) {
        const int u = wid + 2 * k;                  // 32 x 1-KB units
        __builtin_amdgcn_global_load_lds(
            (const __attribute__((address_space(1))) void*)(src0 + (u << 10) + lane * 16),
            (__attribute__((address_space(3))) void*)(&Asm[u << 10]), 16, 0, 0);
    }

    int bgv[4];
    #pragma unroll
    for (int ct = 0; ct < 4; ++ct) bgv[ct] = BG[cw + ct * 16 + lo16];
    const float rs = (*si) * (*sw) / (*so);
    const float zo = (float)(*zpo);

    // per-mt geometry (slab-local): base offset only; swizzle derived from off
    int boff[7];
    #pragma unroll
    for (int mt = 0; mt < 7; ++mt) {
        const int ml = mt * 16 + lo16;              // 0..111 within slab
        const int srow = ml / 56, scol = ml - srow * 56;
        boff[mt] = srow * 8192 + scol * 128 + quad * 16;
    }

    // B stream base for this wave: page (t*8 + c64*4 + quad), offset co*16
    const int8_t* bwav = bp + ((size_t)quad << 12) + ((cw + lo16) << 4);

    int* optr = out + ((size_t)n * CO + cw + lo16) * SPA + quad * 4;

    // issue the 8 B fragments for tap tp into buffer (tp&1)
    #define BLOAD(tp) {                                                        \
        const int8_t* bb = bwav + ((tp) * 8 << 12);                            \
        asm volatile("" : "+v"(bb));                                           \
        bt[(tp) & 1][0] = *(const v4i*)(bb);                                   \
        bt[(tp) & 1][1] = *(const v4i*)(bb + 256);                             \
        bt[(tp) & 1][2] = *(const v4i*)(bb + 512);                             \
        bt[(tp) & 1][3] = *(const v4i*)(bb + 768);                             \
        bt[(tp) & 1][4] = *(const v4i*)(bb + 16384);                           \
        bt[(tp) & 1][5] = *(const v4i*)(bb + 16384 + 256);                     \
        bt[(tp) & 1][6] = *(const v4i*)(bb + 16384 + 512);                     \
        bt[(tp) & 1][7] = *(const v4i*)(bb + 16384 + 768);                     \
    }

    // swizzled LDS address for (tp, mt): bits 7..9 of off == padded col mod 8
    #define AADDR(tp, mt) ({                                                   \
        const int off_ = boff[mt] + ((tp) / 3) * 8192 + ((tp) % 3) * 128;      \
        off_ ^ (((off_ >> 7) & 7) << 4); })

    v4i bt[2][8];                                   // streamed B, tap dbuf
    BLOAD(0);

    v4i acc[7][4];
    #pragma unroll
    for (int mt = 0; mt < 7; ++mt)
        #pragma unroll
        for (int ct = 0; ct < 4; ++ct) acc[mt][ct] = (v4i){0, 0, 0, 0};

    __syncthreads();                                // A slab staged

    // ---- K-loop: flat 63 iters (tp = it/7, mt = it%7), depth-1 A pipeline.
    //      (it+1)'s 2 ds_reads issue under it's 8 MFMAs (~160 cy cover). ----
    v4i a0p[2], a1p[2];
    { const int p = AADDR(0, 0);
      a0p[0] = *(const v4i*)(Asm + p); a1p[0] = *(const v4i*)(Asm + (p ^ 64)); }

    #pragma unroll
    for (int it = 0; it < 63; ++it) {
        const int tp = it / 7, mt = it % 7;
        if (mt == 0 && tp + 1 <= 8) BLOAD(tp + 1);  // B one tap ahead
        if (it + 1 < 63) {                          // A one iter ahead
            const int p = AADDR((it + 1) / 7, (it + 1) % 7);
            a0p[(it + 1) & 1] = *(const v4i*)(Asm + p);
            a1p[(it + 1) & 1] = *(const v4i*)(Asm + (p ^ 64));
        }
        const v4i a0 = a0p[it & 1], a1 = a1p[it & 1];
        #pragma unroll
        for (int ct = 0; ct < 4; ++ct)
            acc[mt][ct] = __builtin_amdgcn_mfma_i32_16x16x64_i8(a0, bt[tp & 1][ct], acc[mt][ct], 0, 0, 0);
        #pragma unroll
        for (int ct = 0; ct < 4; ++ct)
            acc[mt][ct] = __builtin_amdgcn_mfma_i32_16x16x64_i8(a1, bt[tp & 1][4 + ct], acc[mt][ct], 0, 0, 0);
    }
    #undef BLOAD
    #undef AADDR

    // ---- epilogue: requant + 28 direct v4i stores; kernel ends ----
    const int m0 = s2 * 112;
    #pragma unroll
    for (int mt = 0; mt < 7; ++mt) {
        #pragma unroll
        for (int ct = 0; ct < 4; ++ct) {
            v4i vv;
            #pragma unroll
            for (int i4 = 0; i4 < 4; ++i4) {        // C/D row = quad*4+i4
                float yv = rintf((float)(acc[mt][ct][i4] + bgv[ct]) * rs + zo);
                yv = fminf(fmaxf(yv, -128.f), 127.f);
                vv[i4] = (int)yv;
            }
            *(v4i*)(optr + ct * 16 * SPA + m0 + mt * 16) = vv;
        }
    }
}

extern "C" void kernel_launch(void* const* d_in, const int* in_sizes, int n_in,
                              void* d_out, int out_size, void* d_ws, size_t ws_size,
                              hipStream_t stream) {
    const int*   x    = (const int*)d_in[0];
    const int*   wgt  = (const int*)d_in[1];
    const int*   bias = (const int*)d_in[2];
    const float* si   = (const float*)d_in[3];
    const float* sw   = (const float*)d_in[4];
    const float* so   = (const float*)d_in[5];
    const int*   zpi  = (const int*)d_in[6];
    const int*   zpo  = (const int*)d_in[7];
    int* out = (int*)d_out;

    int8_t* xp2 = (int8_t*)d_ws;
    int8_t* bp  = xp2 + XP2_BYTES;
    int*    bg  = (int*)(bp + BP_BYTES);

    prep_kernel<<<HH * NB + 2 * NB + CO, 256, 0, stream>>>(x, wgt, bias, zpi, xp2, bp, bg);
    qconv_mfma<<<1792, 128, 0, stream>>>(xp2, bp, bg, si, sw, so, zpo, out);
}